// Round 3
// baseline (206.584 us; speedup 1.0000x reference)
//
#include <hip/hip_runtime.h>
#include <math.h>

#define NH      6
#define T_IN    2000
#define T_AUD   960000
#define NB      4
#define C_IN    129
#define C_MID   32

// =====================================================================
// k_amp: fused conv1 (129->32, k=5, pad=2) + bias + SiLU + conv2 (1x1, 32->6)
// grid (32 t-tiles of 64, NB), block 512 (8 layers x 4 out-ch each)
// =====================================================================
__global__ __launch_bounds__(512) void k_amp(const float* __restrict__ f0,
                                             const float* __restrict__ mel,
                                             const float* __restrict__ w1,
                                             const float* __restrict__ b1,
                                             const float* __restrict__ w2,
                                             const float* __restrict__ b2,
                                             float* __restrict__ amp) {
    const int b   = blockIdx.y;
    const int t0  = blockIdx.x * 64;
    const int tid = threadIdx.x;
    const int tt    = tid & 63;     // t within tile
    const int layer = tid >> 6;     // 0..7
    const int o0    = layer * 4;

    __shared__ float xl[16][72];        // staged cols [t0-4, t0+68)
    __shared__ float hsil[C_MID][64];   // silu(conv1+bias)

    float acc[4] = {0.f, 0.f, 0.f, 0.f};

    for (int cg = 0; cg < C_IN; cg += 16) {
        const int ng = (C_IN - cg) < 16 ? (C_IN - cg) : 16;
        __syncthreads();
        for (int idx = tid; idx < ng * 18; idx += 512) {
            const int r = idx / 18;
            const int j = idx - r * 18;
            const int c = cg + r;
            const float* row = (c == 0) ? (f0 + b * T_IN)
                                        : (mel + ((size_t)(b * 128 + (c - 1))) * T_IN);
            const int gt = t0 - 4 + j * 4;
            float4 v;
            if (gt >= 0 && gt + 3 < T_IN) {
                v = *(const float4*)(row + gt);
            } else {
                v.x = (gt + 0 >= 0 && gt + 0 < T_IN) ? row[gt + 0] : 0.0f;
                v.y = (gt + 1 >= 0 && gt + 1 < T_IN) ? row[gt + 1] : 0.0f;
                v.z = (gt + 2 >= 0 && gt + 2 < T_IN) ? row[gt + 2] : 0.0f;
                v.w = (gt + 3 >= 0 && gt + 3 < T_IN) ? row[gt + 3] : 0.0f;
            }
            *(float4*)(&xl[r][j * 4]) = v;
        }
        __syncthreads();
        for (int ci = 0; ci < ng; ++ci) {
            const float x0 = xl[ci][tt + 2];
            const float x1 = xl[ci][tt + 3];
            const float x2 = xl[ci][tt + 4];
            const float x3 = xl[ci][tt + 5];
            const float x4 = xl[ci][tt + 6];
            const int cgl = cg + ci;
            #pragma unroll
            for (int oo = 0; oo < 4; ++oo) {
                // wave-uniform -> scalar loads
                const float* wp = w1 + (size_t)(o0 + oo) * (C_IN * 5) + cgl * 5;
                acc[oo] = fmaf(wp[0], x0, acc[oo]);
                acc[oo] = fmaf(wp[1], x1, acc[oo]);
                acc[oo] = fmaf(wp[2], x2, acc[oo]);
                acc[oo] = fmaf(wp[3], x3, acc[oo]);
                acc[oo] = fmaf(wp[4], x4, acc[oo]);
            }
        }
    }

    #pragma unroll
    for (int oo = 0; oo < 4; ++oo) {
        const float v = acc[oo] + b1[o0 + oo];
        hsil[o0 + oo][tt] = v * __builtin_amdgcn_rcpf(1.0f + __expf(-v));
    }
    __syncthreads();

    if (tid < NH * 64) {
        const int h = tid >> 6;     // wave-uniform
        const int t = tid & 63;
        float a = b2[h];
        #pragma unroll
        for (int o = 0; o < C_MID; ++o)
            a = fmaf(w2[h * C_MID + o], hsil[o][t], a);
        const int gt = t0 + t;
        if (gt < T_IN) amp[((size_t)(b * NH + h)) * T_IN + gt] = a;
    }
}

// =====================================================================
// k_prefix: per-batch frame prefix P[i] = 240*f0[0] + 240*sum_{j<i}(f0[j]+f0[j+1])
// grid NB blocks, block 256, 8 frames/thread
// =====================================================================
__global__ void k_prefix(const float* __restrict__ f0, double* __restrict__ P) {
    const int b   = blockIdx.x;
    const int tid = threadIdx.x;
    const float* f0b = f0 + b * T_IN;

    double loc[8];
    double c = 0.0;
    const int base = tid * 8;
    #pragma unroll
    for (int j = 0; j < 8; ++j) {
        const int idx = base + j;
        loc[j] = c;
        if (idx < T_IN - 1) c += (double)f0b[idx] + (double)f0b[idx + 1];
    }
    __shared__ double part[256];
    part[tid] = c;
    __syncthreads();
    double run = c;
    for (int d = 1; d < 256; d <<= 1) {
        const double tadd = (tid >= d) ? part[tid - d] : 0.0;
        __syncthreads();
        run += tadd;
        part[tid] = run;
        __syncthreads();
    }
    const double excl  = run - c;
    const double base0 = 240.0 * (double)f0b[0];
    #pragma unroll
    for (int j = 0; j < 8; ++j) {
        const int idx = base + j;
        if (idx < T_IN) P[b * T_IN + idx] = base0 + 240.0 * (excl + loc[j]);
    }
}

// =====================================================================
// k_main: closed-form phase (no scan) + harmonics + noise
// grid (938, NB), block 256, 4 consecutive samples/thread (float4 IO)
// E(t) = P[i] + n*f0[i] + d*W(n), n = m+1,
// W(n) = 0 (n<=0) | n^2/960 (n<=480) | n-240 (n>480); phase = frac(E/48000)
// =====================================================================
__global__ void k_main(const float* __restrict__ f0, const float* __restrict__ noise,
                       const float* __restrict__ amp, const double* __restrict__ P,
                       const float* __restrict__ amp_logscale, const float* __restrict__ phase_offset,
                       const float* __restrict__ lnv, const float* __restrict__ lnu,
                       float* __restrict__ out) {
    const int b  = blockIdx.y;
    const int g  = blockIdx.x * 256 + threadIdx.x;
    const int t0 = g * 4;
    if (t0 >= T_AUD) return;

    const float*  f0b = f0 + b * T_IN;
    const double* Pb  = P + b * T_IN;

    int iv[4], mv[4];
    #pragma unroll
    for (int j = 0; j < 4; ++j) {
        const int t = t0 + j;
        int u = t - 240; if (u < 0) u = 0;
        int i = u / 480; if (i > 1998) i = 1998;
        iv[j] = i;
        mv[j] = t - i * 480 - 240;
    }
    const bool uni = (iv[0] == iv[3]);   // true except ~1 lane per frame boundary

    double Pi[4]; float fa[4], fd[4];
    if (uni) {
        const double p = Pb[iv[0]];
        const float  a = f0b[iv[0]];
        const float  d = f0b[iv[0] + 1] - a;
        #pragma unroll
        for (int j = 0; j < 4; ++j) { Pi[j] = p; fa[j] = a; fd[j] = d; }
    } else {
        #pragma unroll
        for (int j = 0; j < 4; ++j) {
            Pi[j] = Pb[iv[j]];
            fa[j] = f0b[iv[j]];
            fd[j] = f0b[iv[j] + 1] - fa[j];
        }
    }

    float ph[4], w[4], f0f[4], voiced[4];
    #pragma unroll
    for (int j = 0; j < 4; ++j) {
        const int n = mv[j] + 1;
        const double dn = (double)n;
        const double Wn = (n <= 0) ? 0.0 : ((n <= 480) ? dn * dn * (1.0 / 960.0) : dn - 240.0);
        const double E  = Pi[j] + dn * (double)fa[j] + (double)fd[j] * Wn;
        const double phase = E * (1.0 / 48000.0);
        ph[j] = (float)(phase - floor(phase));

        double wd = ((double)mv[j] + 0.5) * (1.0 / 480.0);
        wd = wd < 0.0 ? 0.0 : (wd > 1.0 ? 1.0 : wd);
        w[j] = (float)wd;
        const double f0u = (double)fa[j] + (double)fd[j] * wd;
        f0f[j] = (float)f0u;
        voiced[j] = (f0f[j] > 1.0f) ? 1.0f : 0.0f;
    }

    const size_t outb = (size_t)b * 7 * T_AUD;
    #pragma unroll
    for (int h = 0; h < NH; ++h) {
        const float kf = (float)(h + 1);
        const float ascale = __expf(amp_logscale[h]);
        const float off = phase_offset[h];
        const float* ab = amp + ((size_t)(b * NH + h)) * T_IN;

        float am[4];
        if (uni) {
            const float a0 = ab[iv[0]];
            const float dd = ab[iv[0] + 1] - a0;
            #pragma unroll
            for (int j = 0; j < 4; ++j) am[j] = fmaf(dd, w[j], a0);
        } else {
            #pragma unroll
            for (int j = 0; j < 4; ++j)
                am[j] = fmaf(ab[iv[j] + 1] - ab[iv[j]], w[j], ab[iv[j]]);
        }

        float r[4];
        #pragma unroll
        for (int j = 0; j < 4; ++j) {
            const float sig = __builtin_amdgcn_rcpf(1.0f + __expf(-am[j]));
            const float arg = kf * ph[j] + off;          // revolutions
            const float fr  = arg - floorf(arg);
            const float sn  = __builtin_amdgcn_sinf(fr); // sin(2*pi*fr)
            const float aa  = __builtin_amdgcn_rcpf(
                1.0f + __expf(-(24000.0f - kf * f0f[j]) * (1.0f / 1200.0f)));
            r[j] = sn * ascale * (2.0f * sig) * (aa * voiced[j]);
        }
        float4 res; res.x = r[0]; res.y = r[1]; res.z = r[2]; res.w = r[3];
        *(float4*)(out + outb + (size_t)h * T_AUD + t0) = res;
    }

    const float nv = __expf(lnv[0]);
    const float nu = __expf(lnu[0]);
    const float4 nz = *(const float4*)(noise + (size_t)b * T_AUD + t0);
    float4 no;
    no.x = nz.x * (voiced[0] > 0.0f ? nv : nu);
    no.y = nz.y * (voiced[1] > 0.0f ? nv : nu);
    no.z = nz.z * (voiced[2] > 0.0f ? nv : nu);
    no.w = nz.w * (voiced[3] > 0.0f ? nv : nu);
    *(float4*)(out + outb + (size_t)6 * T_AUD + t0) = no;
}

extern "C" void kernel_launch(void* const* d_in, const int* in_sizes, int n_in,
                              void* d_out, int out_size, void* d_ws, size_t ws_size,
                              hipStream_t stream) {
    const float* f0   = (const float*)d_in[0];
    const float* mel  = (const float*)d_in[1];
    const float* nois = (const float*)d_in[2];
    const float* w1   = (const float*)d_in[3];
    const float* b1   = (const float*)d_in[4];
    const float* w2   = (const float*)d_in[5];
    const float* b2   = (const float*)d_in[6];
    const float* alog = (const float*)d_in[7];
    const float* poff = (const float*)d_in[8];
    const float* lnv  = (const float*)d_in[9];
    const float* lnu  = (const float*)d_in[10];
    float* out = (float*)d_out;

    // workspace: amp (4*6*2000 f32 = 192000 B) | P (4*2000 f64 = 64000 B)
    float*  amp = (float*)d_ws;
    double* P   = (double*)((char*)d_ws + 192000);

    k_amp<<<dim3(32, NB), 512, 0, stream>>>(f0, mel, w1, b1, w2, b2, amp);
    k_prefix<<<dim3(NB), 256, 0, stream>>>(f0, P);
    k_main<<<dim3((T_AUD / 4 + 255) / 256, NB), 256, 0, stream>>>(
        f0, nois, amp, P, alog, poff, lnv, lnu, out);
}

// Round 4
// 190.761 us; speedup vs baseline: 1.0829x; 1.0829x over previous
//
#include <hip/hip_runtime.h>
#include <math.h>

#define NH      6
#define T_IN    2000
#define T_AUD   960000
#define NB      4
#define C_IN    129
#define C_MID   32
#define CSPLIT  3
#define NC_PER  43          // channels per c-split (43*3 = 129)
#define SPLIT_STRIDE (NB * C_MID * T_IN)   // 256000 floats

// ---------------- conv1 partials (no bias), split over channels ----------------
// grid: x = 8 t-tiles, y = b*4 + og (16), z = csplit (3). block 256.
__global__ void k_conv1(const float* __restrict__ f0, const float* __restrict__ mel,
                        const float* __restrict__ w1, float* __restrict__ hpart) {
    const int t0  = blockIdx.x * 256;
    const int b   = blockIdx.y >> 2;
    const int o0  = (blockIdx.y & 3) * 8;
    const int z   = blockIdx.z;
    const int cbase = z * NC_PER;
    const int tid = threadIdx.x;

    __shared__ float xl[NC_PER][264];   // staged cols [t0-4, t0+260)

    for (int idx = tid; idx < NC_PER * 66; idx += 256) {
        const int r = idx / 66;
        const int j = idx - r * 66;
        const int c = cbase + r;
        const float* row = (c == 0) ? (f0 + b * T_IN)
                                    : (mel + ((size_t)(b * 128 + (c - 1))) * T_IN);
        const int gt = t0 - 4 + j * 4;
        float4 v;
        if (gt >= 0 && gt + 3 < T_IN) {
            v = *(const float4*)(row + gt);
        } else {
            v.x = (gt + 0 >= 0 && gt + 0 < T_IN) ? row[gt + 0] : 0.0f;
            v.y = (gt + 1 >= 0 && gt + 1 < T_IN) ? row[gt + 1] : 0.0f;
            v.z = (gt + 2 >= 0 && gt + 2 < T_IN) ? row[gt + 2] : 0.0f;
            v.w = (gt + 3 >= 0 && gt + 3 < T_IN) ? row[gt + 3] : 0.0f;
        }
        *(float4*)(&xl[r][j * 4]) = v;
    }
    __syncthreads();

    float acc[8];
    #pragma unroll
    for (int oo = 0; oo < 8; ++oo) acc[oo] = 0.0f;

    for (int c = 0; c < NC_PER; ++c) {
        const float x0 = xl[c][tid + 2];
        const float x1 = xl[c][tid + 3];
        const float x2 = xl[c][tid + 4];
        const float x3 = xl[c][tid + 5];
        const float x4 = xl[c][tid + 6];
        const int cg = cbase + c;
        #pragma unroll
        for (int oo = 0; oo < 8; ++oo) {
            const float* wp = w1 + (size_t)(o0 + oo) * (C_IN * 5) + cg * 5;  // wave-uniform -> scalar
            acc[oo] = fmaf(wp[0], x0, acc[oo]);
            acc[oo] = fmaf(wp[1], x1, acc[oo]);
            acc[oo] = fmaf(wp[2], x2, acc[oo]);
            acc[oo] = fmaf(wp[3], x3, acc[oo]);
            acc[oo] = fmaf(wp[4], x4, acc[oo]);
        }
    }

    const int t = t0 + tid;
    if (t < T_IN) {
        #pragma unroll
        for (int oo = 0; oo < 8; ++oo)
            hpart[(size_t)z * SPLIT_STRIDE + ((size_t)(b * C_MID + o0 + oo)) * T_IN + t] = acc[oo];
    }
}

// ---------------- conv2: sum partials + bias, silu, 1x1 conv ----------------
__global__ void k_conv2(const float* __restrict__ hpart, const float* __restrict__ b1,
                        const float* __restrict__ w2, const float* __restrict__ b2,
                        float* __restrict__ amp) {
    const int g = blockIdx.x * 256 + threadIdx.x;
    if (g >= NB * NH * T_IN) return;
    const int b = g / (NH * T_IN);
    const int r = g - b * (NH * T_IN);
    const int h = r / T_IN;
    const int t = r - h * T_IN;
    float acc = b2[h];
    #pragma unroll
    for (int o = 0; o < C_MID; ++o) {
        const size_t base = ((size_t)(b * C_MID + o)) * T_IN + t;
        float v = hpart[base] + hpart[SPLIT_STRIDE + base] + hpart[2 * SPLIT_STRIDE + base] + b1[o];
        const float sg = __builtin_amdgcn_rcpf(1.0f + __expf(-v));
        acc = fmaf(w2[h * C_MID + o], v * sg, acc);
    }
    amp[g] = acc;
}

// =====================================================================
// k_prefix: Pfrac[i] = frac(P[i]/48000), P[i] = 240*f0[0] + 240*sum_{j<i}(f0[j]+f0[j+1])
// grid NB blocks, block 256, 8 frames/thread. f64 internally, f32 out.
// =====================================================================
__global__ void k_prefix(const float* __restrict__ f0, float* __restrict__ Pf) {
    const int b   = blockIdx.x;
    const int tid = threadIdx.x;
    const float* f0b = f0 + b * T_IN;

    double loc[8];
    double c = 0.0;
    const int base = tid * 8;
    #pragma unroll
    for (int j = 0; j < 8; ++j) {
        const int idx = base + j;
        loc[j] = c;
        if (idx < T_IN - 1) c += (double)f0b[idx] + (double)f0b[idx + 1];
    }
    __shared__ double part[256];
    part[tid] = c;
    __syncthreads();
    double run = c;
    for (int d = 1; d < 256; d <<= 1) {
        const double tadd = (tid >= d) ? part[tid - d] : 0.0;
        __syncthreads();
        run += tadd;
        part[tid] = run;
        __syncthreads();
    }
    const double excl  = run - c;
    const double base0 = 240.0 * (double)f0b[0];
    #pragma unroll
    for (int j = 0; j < 8; ++j) {
        const int idx = base + j;
        if (idx < T_IN) {
            const double P = (base0 + 240.0 * (excl + loc[j])) * (1.0 / 48000.0);
            Pf[b * T_IN + idx] = (float)(P - floor(P));
        }
    }
}

// =====================================================================
// k_main: pure-f32 closed-form phase + harmonics + noise.
// grid (938, NB), block 256, 4 consecutive samples/thread.
// Block covers 1024 samples -> spans <= 4 frames; frame data cached in LDS.
// E(t)/48000 = Pfrac[i] + (n*f0[i] + d*W(n))/48000, n = t - 480*i - 239,
// W(n) = 0 (n<=0) | n^2/960 (n<=480) | n-240 (n>480)
// =====================================================================
__global__ __launch_bounds__(256) void k_main(
        const float* __restrict__ f0, const float* __restrict__ noise,
        const float* __restrict__ amp, const float* __restrict__ Pf,
        const float* __restrict__ amp_logscale, const float* __restrict__ phase_offset,
        const float* __restrict__ lnv, const float* __restrict__ lnu,
        float* __restrict__ out) {
    const int b   = blockIdx.y;
    const int tid = threadIdx.x;
    const int s0  = blockIdx.x * 1024;
    const int t0  = s0 + tid * 4;

    __shared__ float sf0[6];      // f0[i_lo .. i_lo+5] (one extra for safety)
    __shared__ float sPf[4];      // Pfrac[i_lo .. i_lo+3]
    __shared__ float sam[NH][5];  // amp rows
    __shared__ float sasc[NH], soff[NH], snv, snu;

    // block-uniform lowest frame index
    const int ulo  = (s0 - 240) < 0 ? 0 : (s0 - 240);
    int i_lo = (unsigned)ulo / 480u;
    if (i_lo > 1998) i_lo = 1998;

    const float* f0b = f0 + b * T_IN;
    const float* Pfb = Pf + b * T_IN;

    if (tid < 6) {
        int idx = i_lo + tid; if (idx > 1999) idx = 1999;
        sf0[tid] = f0b[idx];
    } else if (tid >= 8 && tid < 12) {
        int idx = i_lo + (tid - 8); if (idx > 1999) idx = 1999;
        sPf[tid - 8] = Pfb[idx];
    } else if (tid >= 16 && tid < 46) {
        const int h  = (tid - 16) / 5;
        const int jj = (tid - 16) - h * 5;
        int idx = i_lo + jj; if (idx > 1999) idx = 1999;
        sam[h][jj] = amp[((size_t)(b * NH + h)) * T_IN + idx];
    } else if (tid >= 48 && tid < 54) {
        sasc[tid - 48] = __expf(amp_logscale[tid - 48]);
    } else if (tid >= 56 && tid < 62) {
        soff[tid - 56] = phase_offset[tid - 56];
    } else if (tid == 62) {
        snv = __expf(lnv[0]);
    } else if (tid == 63) {
        snu = __expf(lnu[0]);
    }
    __syncthreads();

    if (t0 >= T_AUD) return;

    const float inv48k = 1.0f / 48000.0f;
    float ph[4], wd[4], f0f[4], voiced[4];
    int li[4];
    #pragma unroll
    for (int j = 0; j < 4; ++j) {
        const int t = t0 + j;
        const int u = (t - 240) < 0 ? 0 : (t - 240);
        int i = (unsigned)u / 480u;
        if (i > 1998) i = 1998;
        li[j] = i - i_lo;
        const int m = t - i * 480 - 240;      // [-240, 719]
        const int n = m + 1;
        const float nf = (float)n;
        const float Wn = (n <= 0) ? 0.0f
                       : ((n <= 480) ? nf * nf * (1.0f / 960.0f) : nf - 240.0f);
        const float fa = sf0[li[j]];
        const float fd = sf0[li[j] + 1] - fa;
        const float pr = sPf[li[j]] + (nf * fa + fd * Wn) * inv48k;
        ph[j] = pr - floorf(pr);

        float w = ((float)m + 0.5f) * (1.0f / 480.0f);
        w = w < 0.0f ? 0.0f : (w > 1.0f ? 1.0f : w);
        wd[j] = w;
        f0f[j] = fmaf(fd, w, fa);
        voiced[j] = (f0f[j] > 1.0f) ? 1.0f : 0.0f;
    }

    const size_t outb = (size_t)b * 7 * T_AUD;
    #pragma unroll
    for (int h = 0; h < NH; ++h) {
        const float kf = (float)(h + 1);
        const float ascale = sasc[h];
        const float off = soff[h];
        float r[4];
        #pragma unroll
        for (int j = 0; j < 4; ++j) {
            const float a0 = sam[h][li[j]];
            const float am = fmaf(sam[h][li[j] + 1] - a0, wd[j], a0);
            const float sig = __builtin_amdgcn_rcpf(1.0f + __expf(-am));
            const float arg = kf * ph[j] + off;            // revolutions
            const float fr  = arg - floorf(arg);
            const float sn  = __builtin_amdgcn_sinf(fr);   // sin(2*pi*fr)
            const float aa  = __builtin_amdgcn_rcpf(
                1.0f + __expf(-(24000.0f - kf * f0f[j]) * (1.0f / 1200.0f)));
            r[j] = sn * ascale * (2.0f * sig) * (aa * voiced[j]);
        }
        float4 res; res.x = r[0]; res.y = r[1]; res.z = r[2]; res.w = r[3];
        *(float4*)(out + outb + (size_t)h * T_AUD + t0) = res;
    }

    const float4 nz = *(const float4*)(noise + (size_t)b * T_AUD + t0);
    float4 no;
    no.x = nz.x * (voiced[0] > 0.0f ? snv : snu);
    no.y = nz.y * (voiced[1] > 0.0f ? snv : snu);
    no.z = nz.z * (voiced[2] > 0.0f ? snv : snu);
    no.w = nz.w * (voiced[3] > 0.0f ? snv : snu);
    *(float4*)(out + outb + (size_t)6 * T_AUD + t0) = no;
}

extern "C" void kernel_launch(void* const* d_in, const int* in_sizes, int n_in,
                              void* d_out, int out_size, void* d_ws, size_t ws_size,
                              hipStream_t stream) {
    const float* f0   = (const float*)d_in[0];
    const float* mel  = (const float*)d_in[1];
    const float* nois = (const float*)d_in[2];
    const float* w1   = (const float*)d_in[3];
    const float* b1   = (const float*)d_in[4];
    const float* w2   = (const float*)d_in[5];
    const float* b2   = (const float*)d_in[6];
    const float* alog = (const float*)d_in[7];
    const float* poff = (const float*)d_in[8];
    const float* lnv  = (const float*)d_in[9];
    const float* lnu  = (const float*)d_in[10];
    float* out = (float*)d_out;

    // workspace: hpart 3*4*32*2000 f32 (3072000 B) | amp 4*6*2000 f32 (192000 B)
    //            | Pfrac 4*2000 f32 (32000 B)
    float* hpart = (float*)d_ws;
    float* amp   = (float*)((char*)d_ws + 3072000);
    float* Pfrac = (float*)((char*)d_ws + 3264000);

    k_conv1<<<dim3(8, 16, CSPLIT), 256, 0, stream>>>(f0, mel, w1, hpart);
    k_conv2<<<dim3((NB * NH * T_IN + 255) / 256), 256, 0, stream>>>(hpart, b1, w2, b2, amp);
    k_prefix<<<dim3(NB), 256, 0, stream>>>(f0, Pfrac);
    k_main<<<dim3((T_AUD + 1023) / 1024, NB), 256, 0, stream>>>(
        f0, nois, amp, Pfrac, alog, poff, lnv, lnu, out);
}

// Round 5
// 188.698 us; speedup vs baseline: 1.0948x; 1.0109x over previous
//
#include <hip/hip_runtime.h>
#include <math.h>

#define NH      6
#define T_IN    2000
#define T_AUD   960000
#define NB      4
#define C_IN    129
#define C_MID   32
#define CSPLIT  3
#define NC_PER  43          // channels per c-split (43*3 = 129)
#define SPLIT_STRIDE (NB * C_MID * T_IN)   // 256000 floats

// ---------------- conv1 partials (no bias), split over channels ----------------
// grid: x = 8 t-tiles, y = b*4 + og (16), z = csplit (3). block 256.
__global__ void k_conv1(const float* __restrict__ f0, const float* __restrict__ mel,
                        const float* __restrict__ w1, float* __restrict__ hpart) {
    const int t0  = blockIdx.x * 256;
    const int b   = blockIdx.y >> 2;
    const int o0  = (blockIdx.y & 3) * 8;
    const int z   = blockIdx.z;
    const int cbase = z * NC_PER;
    const int tid = threadIdx.x;

    __shared__ float xl[NC_PER][264];   // staged cols [t0-4, t0+260)

    for (int idx = tid; idx < NC_PER * 66; idx += 256) {
        const int r = idx / 66;
        const int j = idx - r * 66;
        const int c = cbase + r;
        const float* row = (c == 0) ? (f0 + b * T_IN)
                                    : (mel + ((size_t)(b * 128 + (c - 1))) * T_IN);
        const int gt = t0 - 4 + j * 4;
        float4 v;
        if (gt >= 0 && gt + 3 < T_IN) {
            v = *(const float4*)(row + gt);
        } else {
            v.x = (gt + 0 >= 0 && gt + 0 < T_IN) ? row[gt + 0] : 0.0f;
            v.y = (gt + 1 >= 0 && gt + 1 < T_IN) ? row[gt + 1] : 0.0f;
            v.z = (gt + 2 >= 0 && gt + 2 < T_IN) ? row[gt + 2] : 0.0f;
            v.w = (gt + 3 >= 0 && gt + 3 < T_IN) ? row[gt + 3] : 0.0f;
        }
        *(float4*)(&xl[r][j * 4]) = v;
    }
    __syncthreads();

    float acc[8];
    #pragma unroll
    for (int oo = 0; oo < 8; ++oo) acc[oo] = 0.0f;

    for (int c = 0; c < NC_PER; ++c) {
        const float x0 = xl[c][tid + 2];
        const float x1 = xl[c][tid + 3];
        const float x2 = xl[c][tid + 4];
        const float x3 = xl[c][tid + 5];
        const float x4 = xl[c][tid + 6];
        const int cg = cbase + c;
        #pragma unroll
        for (int oo = 0; oo < 8; ++oo) {
            const float* wp = w1 + (size_t)(o0 + oo) * (C_IN * 5) + cg * 5;  // wave-uniform -> scalar
            acc[oo] = fmaf(wp[0], x0, acc[oo]);
            acc[oo] = fmaf(wp[1], x1, acc[oo]);
            acc[oo] = fmaf(wp[2], x2, acc[oo]);
            acc[oo] = fmaf(wp[3], x3, acc[oo]);
            acc[oo] = fmaf(wp[4], x4, acc[oo]);
        }
    }

    const int t = t0 + tid;
    if (t < T_IN) {
        #pragma unroll
        for (int oo = 0; oo < 8; ++oo)
            hpart[(size_t)z * SPLIT_STRIDE + ((size_t)(b * C_MID + o0 + oo)) * T_IN + t] = acc[oo];
    }
}

// =====================================================================
// k_main2: inline conv2 + inline frame-prefix + closed-form phase + harmonics.
// grid (938, NB), block 256, 4 consecutive samples/thread (block tile 1024).
// Block spans frames i_lo..i_lo+3 (conv2 positions i_lo..i_lo+4).
// E(t)/48000 = Pfrac[i] + (n*f0[i] + d*W(n))/48000, n = t - 480*i - 239,
// W(n) = 0 (n<=0) | n^2/960 (n<=480) | n-240 (n>480)
// P[i] = 240*f0[0] + 240*sum_{j<i}(f0[j]+f0[j+1])  (f64, per-block reduction)
// =====================================================================
__global__ __launch_bounds__(256) void k_main2(
        const float* __restrict__ f0, const float* __restrict__ noise,
        const float* __restrict__ hpart,
        const float* __restrict__ b1, const float* __restrict__ w2,
        const float* __restrict__ b2,
        const float* __restrict__ amp_logscale, const float* __restrict__ phase_offset,
        const float* __restrict__ lnv, const float* __restrict__ lnu,
        float* __restrict__ out) {
    const int b   = blockIdx.y;
    const int tid = threadIdx.x;
    const int s0  = blockIdx.x * 1024;
    const int t0  = s0 + tid * 4;

    __shared__ float  sf0[6];       // f0[i_lo .. i_lo+5] (clamped)
    __shared__ float  sPf[4];       // frac(P[i]/48000), i_lo..i_lo+3
    __shared__ float  smid[C_MID][5];  // silu(conv1+bias) at positions i_lo..i_lo+4
    __shared__ float  sam[NH][5];   // amp rows
    __shared__ float  sasc[NH], soff[NH], snv, snu;
    __shared__ double swsum[4];

    // block-uniform lowest frame index
    const int ulo  = (s0 - 240) < 0 ? 0 : (s0 - 240);
    int i_lo = (unsigned)ulo / 480u;
    if (i_lo > 1998) i_lo = 1998;

    const float* f0b = f0 + b * T_IN;

    // ---- prefix partial: S = sum_{j < i_lo} (f0[j] + f0[j+1]) ----
    double S = 0.0;
    for (int j = tid; j < i_lo; j += 256)
        S += (double)f0b[j] + (double)f0b[j + 1];
    #pragma unroll
    for (int d = 32; d >= 1; d >>= 1) S += __shfl_down(S, d, 64);
    if ((tid & 63) == 0) swsum[tid >> 6] = S;

    // ---- stage sf0 + constants + smid (silu of conv1 sums) ----
    if (tid < 6) {
        int idx = i_lo + tid; if (idx > 1999) idx = 1999;
        sf0[tid] = f0b[idx];
    } else if (tid >= 8 && tid < 14) {
        sasc[tid - 8] = __expf(amp_logscale[tid - 8]);
    } else if (tid >= 16 && tid < 22) {
        soff[tid - 16] = phase_offset[tid - 16];
    } else if (tid == 22) {
        snv = __expf(lnv[0]);
    } else if (tid == 23) {
        snu = __expf(lnu[0]);
    } else if (tid >= 32 && tid < 32 + C_MID * 5) {
        const int r  = tid - 32;
        const int o  = r / 5;
        const int jj = r - o * 5;
        int idx = i_lo + jj; if (idx > 1999) idx = 1999;
        const size_t base = ((size_t)(b * C_MID + o)) * T_IN + idx;
        const float v = hpart[base] + hpart[SPLIT_STRIDE + base]
                      + hpart[2 * SPLIT_STRIDE + base] + b1[o];
        smid[o][jj] = v * __builtin_amdgcn_rcpf(1.0f + __expf(-v));
    }
    __syncthreads();

    // ---- conv2 (1x1, 32->6) at the 5 positions ----
    if (tid < NH * 5) {
        const int h  = tid / 5;
        const int jj = tid - h * 5;
        float a = b2[h];
        #pragma unroll
        for (int o = 0; o < C_MID; ++o)
            a = fmaf(w2[h * C_MID + o], smid[o][jj], a);
        sam[h][jj] = a;
    }
    // ---- Pfrac recurrence (thread 32, f64) ----
    if (tid == 32) {
        double P = 240.0 * (double)f0b[0]
                 + 240.0 * (swsum[0] + swsum[1] + swsum[2] + swsum[3]);
        #pragma unroll
        for (int k = 0; k < 4; ++k) {
            const double q = P * (1.0 / 48000.0);
            sPf[k] = (float)(q - floor(q));
            P += 240.0 * ((double)sf0[k] + (double)sf0[k + 1]);
        }
    }
    __syncthreads();

    if (t0 >= T_AUD) return;

    const float inv48k = 1.0f / 48000.0f;
    float ph[4], wd[4], f0f[4], voiced[4];
    int li[4];
    #pragma unroll
    for (int j = 0; j < 4; ++j) {
        const int t = t0 + j;
        const int u = (t - 240) < 0 ? 0 : (t - 240);
        int i = (unsigned)u / 480u;
        if (i > 1998) i = 1998;
        li[j] = i - i_lo;
        const int m = t - i * 480 - 240;      // [-240, 719]
        const int n = m + 1;
        const float nf = (float)n;
        const float Wn = (n <= 0) ? 0.0f
                       : ((n <= 480) ? nf * nf * (1.0f / 960.0f) : nf - 240.0f);
        const float fa = sf0[li[j]];
        const float fd = sf0[li[j] + 1] - fa;
        const float pr = sPf[li[j]] + (nf * fa + fd * Wn) * inv48k;
        ph[j] = pr - floorf(pr);

        float w = ((float)m + 0.5f) * (1.0f / 480.0f);
        w = w < 0.0f ? 0.0f : (w > 1.0f ? 1.0f : w);
        wd[j] = w;
        f0f[j] = fmaf(fd, w, fa);
        voiced[j] = (f0f[j] > 1.0f) ? 1.0f : 0.0f;
    }

    const size_t outb = (size_t)b * 7 * T_AUD;
    #pragma unroll
    for (int h = 0; h < NH; ++h) {
        const float kf = (float)(h + 1);
        const float ascale = sasc[h];
        const float off = soff[h];
        float r[4];
        #pragma unroll
        for (int j = 0; j < 4; ++j) {
            const float a0 = sam[h][li[j]];
            const float am = fmaf(sam[h][li[j] + 1] - a0, wd[j], a0);
            const float sig = __builtin_amdgcn_rcpf(1.0f + __expf(-am));
            const float arg = kf * ph[j] + off;            // revolutions
            const float fr  = arg - floorf(arg);
            const float sn  = __builtin_amdgcn_sinf(fr);   // sin(2*pi*fr)
            const float aa  = __builtin_amdgcn_rcpf(
                1.0f + __expf(-(24000.0f - kf * f0f[j]) * (1.0f / 1200.0f)));
            r[j] = sn * ascale * (2.0f * sig) * (aa * voiced[j]);
        }
        float4 res; res.x = r[0]; res.y = r[1]; res.z = r[2]; res.w = r[3];
        *(float4*)(out + outb + (size_t)h * T_AUD + t0) = res;
    }

    const float4 nz = *(const float4*)(noise + (size_t)b * T_AUD + t0);
    float4 no;
    no.x = nz.x * (voiced[0] > 0.0f ? snv : snu);
    no.y = nz.y * (voiced[1] > 0.0f ? snv : snu);
    no.z = nz.z * (voiced[2] > 0.0f ? snv : snu);
    no.w = nz.w * (voiced[3] > 0.0f ? snv : snu);
    *(float4*)(out + outb + (size_t)6 * T_AUD + t0) = no;
}

extern "C" void kernel_launch(void* const* d_in, const int* in_sizes, int n_in,
                              void* d_out, int out_size, void* d_ws, size_t ws_size,
                              hipStream_t stream) {
    const float* f0   = (const float*)d_in[0];
    const float* mel  = (const float*)d_in[1];
    const float* nois = (const float*)d_in[2];
    const float* w1   = (const float*)d_in[3];
    const float* b1   = (const float*)d_in[4];
    const float* w2   = (const float*)d_in[5];
    const float* b2   = (const float*)d_in[6];
    const float* alog = (const float*)d_in[7];
    const float* poff = (const float*)d_in[8];
    const float* lnv  = (const float*)d_in[9];
    const float* lnu  = (const float*)d_in[10];
    float* out = (float*)d_out;

    // workspace: hpart 3*4*32*2000 f32 (3072000 B)
    float* hpart = (float*)d_ws;

    k_conv1<<<dim3(8, 16, CSPLIT), 256, 0, stream>>>(f0, mel, w1, hpart);
    k_main2<<<dim3((T_AUD + 1023) / 1024, NB), 256, 0, stream>>>(
        f0, nois, hpart, b1, w2, b2, alog, poff, lnv, lnu, out);
}